// Round 3
// baseline (254.550 us; speedup 1.0000x reference)
//
#include <hip/hip_runtime.h>
#include <math.h>

// Problem constants
namespace {
constexpr int kB  = 64;
constexpr int kNi = 2048;
constexpr int kDi = 8;
constexpr int kNo = 32;
constexpr int kDo = 16;

constexpr int kThreads   = 512;               // 8 waves
constexpr int kNChunks   = 128;               // n-chunks
constexpr int kNPerChunk = kNi / kNChunks;    // 16 n per workgroup
constexpr int kStageN    = 2;                 // n per LDS stage (32 KB)
constexpr int kStages    = kNPerChunk / kStageN;  // 8
constexpr int kWFloatsPerN = kNo * kDo * kDi; // 4096 floats = 16 KB
constexpr int kSeg = kNo * kDo;               // 512 floats per (b) s-slice
constexpr int kBGroups  = 4;                  // b-groups -> grid 512
constexpr int kBPerWave = 2;                  // 2 b's per wave
constexpr int kRGroups = 8;                   // reduce stage-1 chunk groups
}

// ---------------------------------------------------------------------------
// Pass kernel: recompute x_hat tiles from W (LDS-staged, 32 KB stages) and
// accumulate s_partial[chunk][b][o][d] with c = softmax_o(vsum . x_hat).
// PASS==0: uniform coupling (1/32 applied in finish).
// Grid 512 = 128 chunks x 4 b-groups; 8 waves/block; wave wv owns 2 b's.
// lane -> (o = lane&31, half = lane>>5 covering d in [half*8, half*8+8)).
// 2 blocks/CU co-resident (64 KB LDS) -> 4 waves/SIMD.
// ---------------------------------------------------------------------------
template<int PASS>
__global__ __launch_bounds__(kThreads, 4)
void caps_pass(const float* __restrict__ xg, const float* __restrict__ Wg,
               const float* __restrict__ vsum, float* __restrict__ partial)
{
    __shared__ float lds[kStageN * kWFloatsPerN];   // 32768 B

    const int tid    = threadIdx.x;
    const int nchunk = blockIdx.x & (kNChunks - 1); // 0..127
    const int bg     = blockIdx.x >> 7;             // 0..3
    const int wv     = tid >> 6;                    // 0..7
    const int lane   = tid & 63;
    const int o      = lane & 31;
    const int half   = lane >> 5;
    const int bbase  = bg * 16 + wv * kBPerWave;    // 2 b's per wave

    float vs[kBPerWave][8];
    float sacc[kBPerWave][8];
#pragma unroll
    for (int b2 = 0; b2 < kBPerWave; ++b2) {
#pragma unroll
        for (int j = 0; j < 8; ++j) sacc[b2][j] = 0.0f;
        if (PASS > 0) {
            const float4* vp = reinterpret_cast<const float4*>(
                vsum + (size_t)(bbase + b2) * kSeg + o * kDo + half * 8);
            float4 a = vp[0], b4 = vp[1];
            vs[b2][0] = a.x;  vs[b2][1] = a.y;  vs[b2][2] = a.z;  vs[b2][3] = a.w;
            vs[b2][4] = b4.x; vs[b2][5] = b4.y; vs[b2][6] = b4.z; vs[b2][7] = b4.w;
        }
    }

    const float4* lds4 = reinterpret_cast<const float4*>(lds);

    for (int stage = 0; stage < kStages; ++stage) {
        __syncthreads();   // all waves done reading previous stage
        {
            const size_t n0 = (size_t)nchunk * kNPerChunk + stage * kStageN;
            const float4* src = reinterpret_cast<const float4*>(Wg) + n0 * (kWFloatsPerN / 4);
            float4* dst = reinterpret_cast<float4*>(lds);
#pragma unroll
            for (int k = 0; k < (kStageN * kWFloatsPerN / 4) / kThreads; ++k) {  // 4
                int idx = k * kThreads + tid;
                int swz = idx ^ ((idx >> 5) & 7);   // XOR-swizzle, matches read side
                dst[swz] = src[idx];
            }
        }
        __syncthreads();

#pragma unroll
        for (int nn = 0; nn < kStageN; ++nn) {
            // My W fragment: W[n, o, half*8 + dd, i], dd,i in [0,8) -> 64 floats
            float wf[64];
            {
                const int base4 = nn * (kWFloatsPerN / 4) + o * 32 + half * 16;
#pragma unroll
                for (int j4 = 0; j4 < 16; ++j4) {
                    float4 w4 = lds4[(base4 + j4) ^ (o & 7)];
                    wf[j4 * 4 + 0] = w4.x; wf[j4 * 4 + 1] = w4.y;
                    wf[j4 * 4 + 2] = w4.z; wf[j4 * 4 + 3] = w4.w;
                }
            }
            const int n = nchunk * kNPerChunk + stage * kStageN + nn;

#pragma unroll
            for (int b2 = 0; b2 < kBPerWave; ++b2) {
                const int b = bbase + b2;
                const float4* xp = reinterpret_cast<const float4*>(
                    xg + ((size_t)b * kNi + n) * kDi);
                float4 xa = xp[0], xb = xp[1];
                float xr[8] = {xa.x, xa.y, xa.z, xa.w, xb.x, xb.y, xb.z, xb.w};

                // x_hat for my (o, d-half): 8 values
                float xh[8];
#pragma unroll
                for (int dd = 0; dd < 8; ++dd) {
                    float acc = 0.0f;
#pragma unroll
                    for (int i = 0; i < 8; ++i) acc = fmaf(xr[i], wf[dd * 8 + i], acc);
                    xh[dd] = acc;
                }

                float c;
                if (PASS == 0) {
                    c = 1.0f;  // uniform coupling; 1/32 applied in finish
                } else {
                    float pl = 0.0f;
#pragma unroll
                    for (int dd = 0; dd < 8; ++dd) pl = fmaf(vs[b2][dd], xh[dd], pl);
                    float L = pl + __shfl_xor(pl, 32);   // add other d-half
                    float m = L;
#pragma unroll
                    for (int msk = 16; msk >= 1; msk >>= 1)
                        m = fmaxf(m, __shfl_xor(m, msk));
                    float e = __expf(L - m);
                    float sm = e;
#pragma unroll
                    for (int msk = 16; msk >= 1; msk >>= 1)
                        sm += __shfl_xor(sm, msk);
                    c = e / sm;
                }
#pragma unroll
                for (int dd = 0; dd < 8; ++dd)
                    sacc[b2][dd] = fmaf(c, xh[dd], sacc[b2][dd]);
            }
        }
    }

    // Flush partial s for my 2 b's: layout [chunk][b][lane*8] (coalesced)
#pragma unroll
    for (int b2 = 0; b2 < kBPerWave; ++b2) {
        float* pp = partial + ((size_t)nchunk * kB + (bbase + b2)) * kSeg + lane * 8;
        reinterpret_cast<float4*>(pp)[0] =
            make_float4(sacc[b2][0], sacc[b2][1], sacc[b2][2], sacc[b2][3]);
        reinterpret_cast<float4*>(pp)[1] =
            make_float4(sacc[b2][4], sacc[b2][5], sacc[b2][6], sacc[b2][7]);
    }
}

// ---------------------------------------------------------------------------
// Reduce stage 1: 512 blocks (b x 8 chunk-groups), each sums 16 chunks.
// ---------------------------------------------------------------------------
__global__ __launch_bounds__(512, 2)
void caps_reduce1(const float* __restrict__ partial, float* __restrict__ partial2)
{
    const int g = blockIdx.x & (kRGroups - 1);
    const int b = blockIdx.x >> 3;
    const int t = threadIdx.x;

    const float* p = partial + (size_t)b * kSeg + t
                   + (size_t)(g * (kNChunks / kRGroups)) * (kB * kSeg);
    float a0 = 0, a1 = 0, a2 = 0, a3 = 0;
#pragma unroll
    for (int k = 0; k < kNChunks / kRGroups; k += 4) {
        a0 += p[(size_t)(k + 0) * (kB * kSeg)];
        a1 += p[(size_t)(k + 1) * (kB * kSeg)];
        a2 += p[(size_t)(k + 2) * (kB * kSeg)];
        a3 += p[(size_t)(k + 3) * (kB * kSeg)];
    }
    partial2[((size_t)b * kRGroups + g) * kSeg + t] = (a0 + a1) + (a2 + a3);
}

// ---------------------------------------------------------------------------
// Finish: sum 8 group-partials -> s[b,o,d]; squash; update vsum / write out.
// Thread t -> element (o = (t>>3)&31, d = (t>>8)*8 + (t&7)).
// ---------------------------------------------------------------------------
template<int PASS>
__global__ __launch_bounds__(512, 2)
void caps_finish(const float* __restrict__ partial2, float* __restrict__ vsum,
                 float* __restrict__ out)
{
    const int b = blockIdx.x;
    const int t = threadIdx.x;

    float s = 0.0f;
#pragma unroll
    for (int g = 0; g < kRGroups; ++g)
        s += partial2[((size_t)b * kRGroups + g) * kSeg + t];
    if (PASS == 0) s *= (1.0f / 32.0f);   // uniform coupling 1/No

    __shared__ float s_lds[512];
    __shared__ float f_lds[32];
    s_lds[t] = s;
    __syncthreads();
    if (t < 32) {
        float n2 = 0.0f;
#pragma unroll
        for (int d = 0; d < 16; ++d) {
            float val = s_lds[(d >> 3) * 256 + t * 8 + (d & 7)];
            n2 = fmaf(val, val, n2);
        }
        f_lds[t] = sqrtf(n2) / (1.0f + n2);   // ||s|| / (1 + ||s||^2)
    }
    __syncthreads();

    const int o = (t >> 3) & 31;
    const int d = ((t >> 8) << 3) | (t & 7);
    const float v = f_lds[o] * s;

    if (PASS == 0)      vsum[(size_t)b * kSeg + o * kDo + d] = v;
    else if (PASS == 1) vsum[(size_t)b * kSeg + o * kDo + d] += v;
    else                out[(size_t)b * kSeg + o * kDo + d] = v;
}

// ---------------------------------------------------------------------------
extern "C" void kernel_launch(void* const* d_in, const int* in_sizes, int n_in,
                              void* d_out, int out_size, void* d_ws, size_t ws_size,
                              hipStream_t stream)
{
    const float* x = (const float*)d_in[0];   // (64, 2048, 8)
    const float* W = (const float*)d_in[1];   // (2048, 32, 16, 8)
    float* out = (float*)d_out;               // (64, 32, 16)

    float* partial  = (float*)d_ws;           // [128][64][512] = 16 MB
    float* vsum     = partial + (size_t)kNChunks * kB * kSeg;       // 128 KB
    float* partial2 = vsum + (size_t)kB * kSeg;                     // 1 MB

    const dim3 gp(kNChunks * kBGroups), bp(kThreads);
    const dim3 g1(kB * kRGroups), b1(512);
    const dim3 g2(kB), b2(512);

    caps_pass<0><<<gp, bp, 0, stream>>>(x, W, vsum, partial);
    caps_reduce1<<<g1, b1, 0, stream>>>(partial, partial2);
    caps_finish<0><<<g2, b2, 0, stream>>>(partial2, vsum, out);
    caps_pass<1><<<gp, bp, 0, stream>>>(x, W, vsum, partial);
    caps_reduce1<<<g1, b1, 0, stream>>>(partial, partial2);
    caps_finish<1><<<g2, b2, 0, stream>>>(partial2, vsum, out);
    caps_pass<2><<<gp, bp, 0, stream>>>(x, W, vsum, partial);
    caps_reduce1<<<g1, b1, 0, stream>>>(partial, partial2);
    caps_finish<2><<<g2, b2, 0, stream>>>(partial2, vsum, out);
}

// Round 4
// 176.821 us; speedup vs baseline: 1.4396x; 1.4396x over previous
//
#include <hip/hip_runtime.h>
#include <math.h>

// Problem constants
namespace {
constexpr int kB  = 64;
constexpr int kNi = 2048;
constexpr int kDi = 8;
constexpr int kNo = 32;
constexpr int kDo = 16;

constexpr int kThreads   = 512;               // 8 waves
constexpr int kNChunks   = 128;               // n-chunks
constexpr int kNPerChunk = kNi / kNChunks;    // 16 n per workgroup
constexpr int kStageN    = 2;                 // n per LDS stage (32 KB)
constexpr int kStages    = kNPerChunk / kStageN;  // 8
constexpr int kWFloatsPerN = kNo * kDo * kDi; // 4096 floats = 16 KB
constexpr int kSeg = kNo * kDo;               // 512 floats per (b) s-slice
constexpr int kBGroups  = 4;                  // b-groups -> grid 512
constexpr int kBPerWave = 2;                  // 2 b's per wave
constexpr int kRGroups = 8;                   // reduce stage-1 chunk groups
}

// ---------------------------------------------------------------------------
// Pass kernel: recompute x_hat tiles from W (LDS-staged, 32 KB stages) and
// accumulate s_partial[chunk][b][o][d] with c = softmax_o(vsum . x_hat).
// PASS==0: uniform coupling (1/32 applied in finish).
// Grid 512 = 128 chunks x 4 b-groups; 8 waves/block; wave wv owns 2 b's.
// lane -> (o = lane&31, half = lane>>5 covering d in [half*8, half*8+8)).
// __launch_bounds__(512, 2): 2 blocks/CU -> 4 waves/SIMD -> 128-VGPR cap.
// (Empirical: arg2 behaves as min BLOCKS/CU on this toolchain; (512,4) and
// (1024,4) both snapped VGPR to 64 and spilled wf[64] -> 45 MB scratch.)
// ---------------------------------------------------------------------------
template<int PASS>
__global__ __launch_bounds__(kThreads, 2)
void caps_pass(const float* __restrict__ xg, const float* __restrict__ Wg,
               const float* __restrict__ vsum, float* __restrict__ partial)
{
    __shared__ float lds[kStageN * kWFloatsPerN];   // 32768 B

    const int tid    = threadIdx.x;
    const int nchunk = blockIdx.x & (kNChunks - 1); // 0..127
    const int bg     = blockIdx.x >> 7;             // 0..3
    const int wv     = tid >> 6;                    // 0..7
    const int lane   = tid & 63;
    const int o      = lane & 31;
    const int half   = lane >> 5;
    const int bbase  = bg * 16 + wv * kBPerWave;    // 2 b's per wave

    float vs[kBPerWave][8];
    float sacc[kBPerWave][8];
#pragma unroll
    for (int b2 = 0; b2 < kBPerWave; ++b2) {
#pragma unroll
        for (int j = 0; j < 8; ++j) sacc[b2][j] = 0.0f;
        if (PASS > 0) {
            const float4* vp = reinterpret_cast<const float4*>(
                vsum + (size_t)(bbase + b2) * kSeg + o * kDo + half * 8);
            float4 a = vp[0], b4 = vp[1];
            vs[b2][0] = a.x;  vs[b2][1] = a.y;  vs[b2][2] = a.z;  vs[b2][3] = a.w;
            vs[b2][4] = b4.x; vs[b2][5] = b4.y; vs[b2][6] = b4.z; vs[b2][7] = b4.w;
        }
    }

    const float4* lds4 = reinterpret_cast<const float4*>(lds);

    for (int stage = 0; stage < kStages; ++stage) {
        __syncthreads();   // all waves done reading previous stage
        {
            const size_t n0 = (size_t)nchunk * kNPerChunk + stage * kStageN;
            const float4* src = reinterpret_cast<const float4*>(Wg) + n0 * (kWFloatsPerN / 4);
            float4* dst = reinterpret_cast<float4*>(lds);
#pragma unroll
            for (int k = 0; k < (kStageN * kWFloatsPerN / 4) / kThreads; ++k) {  // 4
                int idx = k * kThreads + tid;
                int swz = idx ^ ((idx >> 5) & 7);   // XOR-swizzle, matches read side
                dst[swz] = src[idx];
            }
        }
        __syncthreads();

#pragma unroll
        for (int nn = 0; nn < kStageN; ++nn) {
            // My W fragment: W[n, o, half*8 + dd, i], dd,i in [0,8) -> 64 floats
            float wf[64];
            {
                const int base4 = nn * (kWFloatsPerN / 4) + o * 32 + half * 16;
#pragma unroll
                for (int j4 = 0; j4 < 16; ++j4) {
                    float4 w4 = lds4[(base4 + j4) ^ (o & 7)];
                    wf[j4 * 4 + 0] = w4.x; wf[j4 * 4 + 1] = w4.y;
                    wf[j4 * 4 + 2] = w4.z; wf[j4 * 4 + 3] = w4.w;
                }
            }
            const int n = nchunk * kNPerChunk + stage * kStageN + nn;

#pragma unroll
            for (int b2 = 0; b2 < kBPerWave; ++b2) {
                const int b = bbase + b2;
                const float4* xp = reinterpret_cast<const float4*>(
                    xg + ((size_t)b * kNi + n) * kDi);
                float4 xa = xp[0], xb = xp[1];
                float xr[8] = {xa.x, xa.y, xa.z, xa.w, xb.x, xb.y, xb.z, xb.w};

                // x_hat for my (o, d-half): 8 values
                float xh[8];
#pragma unroll
                for (int dd = 0; dd < 8; ++dd) {
                    float acc = 0.0f;
#pragma unroll
                    for (int i = 0; i < 8; ++i) acc = fmaf(xr[i], wf[dd * 8 + i], acc);
                    xh[dd] = acc;
                }

                float c;
                if (PASS == 0) {
                    c = 1.0f;  // uniform coupling; 1/32 applied in finish
                } else {
                    float pl = 0.0f;
#pragma unroll
                    for (int dd = 0; dd < 8; ++dd) pl = fmaf(vs[b2][dd], xh[dd], pl);
                    float L = pl + __shfl_xor(pl, 32);   // add other d-half
                    float m = L;
#pragma unroll
                    for (int msk = 16; msk >= 1; msk >>= 1)
                        m = fmaxf(m, __shfl_xor(m, msk));
                    float e = __expf(L - m);
                    float sm = e;
#pragma unroll
                    for (int msk = 16; msk >= 1; msk >>= 1)
                        sm += __shfl_xor(sm, msk);
                    c = e / sm;
                }
#pragma unroll
                for (int dd = 0; dd < 8; ++dd)
                    sacc[b2][dd] = fmaf(c, xh[dd], sacc[b2][dd]);
            }
        }
    }

    // Flush partial s for my 2 b's: layout [chunk][b][lane*8] (coalesced)
#pragma unroll
    for (int b2 = 0; b2 < kBPerWave; ++b2) {
        float* pp = partial + ((size_t)nchunk * kB + (bbase + b2)) * kSeg + lane * 8;
        reinterpret_cast<float4*>(pp)[0] =
            make_float4(sacc[b2][0], sacc[b2][1], sacc[b2][2], sacc[b2][3]);
        reinterpret_cast<float4*>(pp)[1] =
            make_float4(sacc[b2][4], sacc[b2][5], sacc[b2][6], sacc[b2][7]);
    }
}

// ---------------------------------------------------------------------------
// Reduce stage 1: 512 blocks (b x 8 chunk-groups), each sums 16 chunks.
// ---------------------------------------------------------------------------
__global__ __launch_bounds__(512, 2)
void caps_reduce1(const float* __restrict__ partial, float* __restrict__ partial2)
{
    const int g = blockIdx.x & (kRGroups - 1);
    const int b = blockIdx.x >> 3;
    const int t = threadIdx.x;

    const float* p = partial + (size_t)b * kSeg + t
                   + (size_t)(g * (kNChunks / kRGroups)) * (kB * kSeg);
    float a0 = 0, a1 = 0, a2 = 0, a3 = 0;
#pragma unroll
    for (int k = 0; k < kNChunks / kRGroups; k += 4) {
        a0 += p[(size_t)(k + 0) * (kB * kSeg)];
        a1 += p[(size_t)(k + 1) * (kB * kSeg)];
        a2 += p[(size_t)(k + 2) * (kB * kSeg)];
        a3 += p[(size_t)(k + 3) * (kB * kSeg)];
    }
    partial2[((size_t)b * kRGroups + g) * kSeg + t] = (a0 + a1) + (a2 + a3);
}

// ---------------------------------------------------------------------------
// Finish: sum 8 group-partials -> s[b,o,d]; squash; update vsum / write out.
// Thread t -> element (o = (t>>3)&31, d = (t>>8)*8 + (t&7)).
// ---------------------------------------------------------------------------
template<int PASS>
__global__ __launch_bounds__(512, 2)
void caps_finish(const float* __restrict__ partial2, float* __restrict__ vsum,
                 float* __restrict__ out)
{
    const int b = blockIdx.x;
    const int t = threadIdx.x;

    float s = 0.0f;
#pragma unroll
    for (int g = 0; g < kRGroups; ++g)
        s += partial2[((size_t)b * kRGroups + g) * kSeg + t];
    if (PASS == 0) s *= (1.0f / 32.0f);   // uniform coupling 1/No

    __shared__ float s_lds[512];
    __shared__ float f_lds[32];
    s_lds[t] = s;
    __syncthreads();
    if (t < 32) {
        float n2 = 0.0f;
#pragma unroll
        for (int d = 0; d < 16; ++d) {
            float val = s_lds[(d >> 3) * 256 + t * 8 + (d & 7)];
            n2 = fmaf(val, val, n2);
        }
        f_lds[t] = sqrtf(n2) / (1.0f + n2);   // ||s|| / (1 + ||s||^2)
    }
    __syncthreads();

    const int o = (t >> 3) & 31;
    const int d = ((t >> 8) << 3) | (t & 7);
    const float v = f_lds[o] * s;

    if (PASS == 0)      vsum[(size_t)b * kSeg + o * kDo + d] = v;
    else if (PASS == 1) vsum[(size_t)b * kSeg + o * kDo + d] += v;
    else                out[(size_t)b * kSeg + o * kDo + d] = v;
}

// ---------------------------------------------------------------------------
extern "C" void kernel_launch(void* const* d_in, const int* in_sizes, int n_in,
                              void* d_out, int out_size, void* d_ws, size_t ws_size,
                              hipStream_t stream)
{
    const float* x = (const float*)d_in[0];   // (64, 2048, 8)
    const float* W = (const float*)d_in[1];   // (2048, 32, 16, 8)
    float* out = (float*)d_out;               // (64, 32, 16)

    float* partial  = (float*)d_ws;           // [128][64][512] = 16 MB
    float* vsum     = partial + (size_t)kNChunks * kB * kSeg;       // 128 KB
    float* partial2 = vsum + (size_t)kB * kSeg;                     // 1 MB

    const dim3 gp(kNChunks * kBGroups), bp(kThreads);
    const dim3 g1(kB * kRGroups), b1(512);
    const dim3 g2(kB), b2(512);

    caps_pass<0><<<gp, bp, 0, stream>>>(x, W, vsum, partial);
    caps_reduce1<<<g1, b1, 0, stream>>>(partial, partial2);
    caps_finish<0><<<g2, b2, 0, stream>>>(partial2, vsum, out);
    caps_pass<1><<<gp, bp, 0, stream>>>(x, W, vsum, partial);
    caps_reduce1<<<g1, b1, 0, stream>>>(partial, partial2);
    caps_finish<1><<<g2, b2, 0, stream>>>(partial2, vsum, out);
    caps_pass<2><<<gp, bp, 0, stream>>>(x, W, vsum, partial);
    caps_reduce1<<<g1, b1, 0, stream>>>(partial, partial2);
    caps_finish<2><<<g2, b2, 0, stream>>>(partial2, vsum, out);
}

// Round 5
// 138.711 us; speedup vs baseline: 1.8351x; 1.2747x over previous
//
#include <hip/hip_runtime.h>
#include <hip/hip_bf16.h>
#include <math.h>

// Problem constants
namespace {
constexpr int kB  = 64;
constexpr int kNi = 2048;
constexpr int kDi = 8;
constexpr int kNo = 32;
constexpr int kDo = 16;

constexpr int kThreads    = 512;                 // 8 waves
constexpr int kNBlocks    = 256;                 // n-chunks = grid = 1 block/CU
constexpr int kNPerBlock  = kNi / kNBlocks;      // 8 n per block
constexpr int kWFloatsPerN = kNo * kDo * kDi;    // 4096 floats = 16 KB
constexpr int kSeg = kNo * kDo;                  // 512 od elements
}

// ---------------------------------------------------------------------------
// Pass kernel. Block owns 8 n's (full W slab staged once into 128 KB LDS,
// ONE barrier) and ALL 64 b's: wave wv owns b in [wv*8, wv*8+8).
// lane -> (o = lane&31, half = lane>>5 covering d in [half*8, half*8+8)).
// Per n: wf[64] <- LDS (16 x ds_read_b128, XOR-swizzled), amortized over 8 b.
// x loads are wave-uniform (readfirstlane'd wv) -> s_load broadcasts.
// c = softmax_o(vsum . x_hat); PASS==0 uniform (1/32 applied in finish).
// Partials: bf16, layout [b][chunk][od], one int4 store per (lane, b).
// __launch_bounds__(512,1): 1 block/CU, 2 waves/SIMD, 256-VGPR cap
// (empirical: arg2 acts as min blocks/CU on this toolchain).
// ---------------------------------------------------------------------------
template<int PASS>
__global__ __launch_bounds__(kThreads, 1)
void caps_pass(const float* __restrict__ xg, const float* __restrict__ Wg,
               const float* __restrict__ vsum, __hip_bfloat16* __restrict__ partial)
{
    __shared__ float lds[kNPerBlock * kWFloatsPerN];   // 131072 B

    const int tid    = threadIdx.x;
    const int nchunk = blockIdx.x;                     // 0..255
    const int wv     = __builtin_amdgcn_readfirstlane(tid >> 6);  // 0..7
    const int lane   = tid & 63;
    const int o      = lane & 31;
    const int half   = lane >> 5;
    const int bbase  = wv * 8;                         // 8 b's per wave

    // ---- stage all 8 W tiles (128 KB), XOR-swizzled for the read side ----
    {
        const float4* src = reinterpret_cast<const float4*>(Wg)
                          + (size_t)nchunk * kNPerBlock * (kWFloatsPerN / 4);
        float4* dst = reinterpret_cast<float4*>(lds);
#pragma unroll
        for (int k = 0; k < (kNPerBlock * kWFloatsPerN / 4) / kThreads; ++k) {  // 16
            int idx = k * kThreads + tid;
            int swz = idx ^ ((idx >> 5) & 7);
            dst[swz] = src[idx];
        }
    }

    float vs[8][8];
    float sacc[8][8];
#pragma unroll
    for (int b2 = 0; b2 < 8; ++b2) {
#pragma unroll
        for (int j = 0; j < 8; ++j) sacc[b2][j] = 0.0f;
        if (PASS > 0) {
            const float4* vp = reinterpret_cast<const float4*>(
                vsum + (size_t)(bbase + b2) * kSeg + o * kDo + half * 8);
            float4 a = vp[0], b4 = vp[1];
            vs[b2][0] = a.x;  vs[b2][1] = a.y;  vs[b2][2] = a.z;  vs[b2][3] = a.w;
            vs[b2][4] = b4.x; vs[b2][5] = b4.y; vs[b2][6] = b4.z; vs[b2][7] = b4.w;
        }
    }

    __syncthreads();   // the only barrier

    const float4* lds4 = reinterpret_cast<const float4*>(lds);

    for (int nn = 0; nn < kNPerBlock; ++nn) {
        // wf: W[n, o, half*8 + dd, i], dd,i in [0,8) -> 64 floats
        float wf[64];
        {
            const int base4 = nn * (kWFloatsPerN / 4) + o * 32 + half * 16;
#pragma unroll
            for (int j4 = 0; j4 < 16; ++j4) {
                float4 w4 = lds4[(base4 + j4) ^ (o & 7)];
                wf[j4 * 4 + 0] = w4.x; wf[j4 * 4 + 1] = w4.y;
                wf[j4 * 4 + 2] = w4.z; wf[j4 * 4 + 3] = w4.w;
            }
        }
        const int n = nchunk * kNPerBlock + nn;

#pragma unroll
        for (int b2 = 0; b2 < 8; ++b2) {
            const int b = bbase + b2;
            // wave-uniform address -> scalar (s_load) broadcast
            const float4* xp = reinterpret_cast<const float4*>(
                xg + ((size_t)b * kNi + n) * kDi);
            float4 xa = xp[0], xb = xp[1];
            float xr[8] = {xa.x, xa.y, xa.z, xa.w, xb.x, xb.y, xb.z, xb.w};

            float xh[8];
#pragma unroll
            for (int dd = 0; dd < 8; ++dd) {
                float acc = 0.0f;
#pragma unroll
                for (int i = 0; i < 8; ++i) acc = fmaf(xr[i], wf[dd * 8 + i], acc);
                xh[dd] = acc;
            }

            float c = 1.0f;
            if (PASS > 0) {
                float pl = 0.0f;
#pragma unroll
                for (int dd = 0; dd < 8; ++dd) pl = fmaf(vs[b2][dd], xh[dd], pl);
                float L = pl + __shfl_xor(pl, 32);   // add other d-half
                float m = L;
#pragma unroll
                for (int msk = 16; msk >= 1; msk >>= 1)
                    m = fmaxf(m, __shfl_xor(m, msk));
                float e = __expf(L - m);
                float sm = e;
#pragma unroll
                for (int msk = 16; msk >= 1; msk >>= 1)
                    sm += __shfl_xor(sm, msk);
                c = e / sm;
            }
#pragma unroll
            for (int dd = 0; dd < 8; ++dd)
                sacc[b2][dd] = fmaf(c, xh[dd], sacc[b2][dd]);
        }
    }

    // Flush: partial[b][chunk][od] bf16; my 8 od's are contiguous -> int4 store.
#pragma unroll
    for (int b2 = 0; b2 < 8; ++b2) {
        union { __hip_bfloat162 h[4]; int4 v; } u;
        u.h[0] = __float22bfloat162_rn(make_float2(sacc[b2][0], sacc[b2][1]));
        u.h[1] = __float22bfloat162_rn(make_float2(sacc[b2][2], sacc[b2][3]));
        u.h[2] = __float22bfloat162_rn(make_float2(sacc[b2][4], sacc[b2][5]));
        u.h[3] = __float22bfloat162_rn(make_float2(sacc[b2][6], sacc[b2][7]));
        __hip_bfloat16* pp = partial
            + ((size_t)(bbase + b2) * kNBlocks + nchunk) * kSeg
            + o * kDo + half * 8;
        *reinterpret_cast<int4*>(pp) = u.v;   // 16 B aligned: offset % 8 elems == 0
    }
}

// ---------------------------------------------------------------------------
// Finish: sum partials over 256 chunks -> s[b,od]; squash; vsum / out.
// Grid 256 = (b x od-quarter), 128 threads, one od element per thread.
// Reads are 256 B contiguous per iteration (L3-resident partials).
// ---------------------------------------------------------------------------
template<int PASS>
__global__ __launch_bounds__(128, 4)
void caps_finish(const __hip_bfloat16* __restrict__ partial,
                 float* __restrict__ vsum, float* __restrict__ out)
{
    const int b  = blockIdx.x >> 2;
    const int q  = blockIdx.x & 3;
    const int t  = threadIdx.x;
    const int od = q * 128 + t;

    const __hip_bfloat16* p = partial + (size_t)b * kNBlocks * kSeg + od;
    float s = 0.0f;
#pragma unroll 8
    for (int c = 0; c < kNBlocks; ++c)
        s += __bfloat162float(p[(size_t)c * kSeg]);
    if (PASS == 0) s *= (1.0f / 32.0f);   // uniform coupling 1/No

    __shared__ float sq[128];
    __shared__ float fo[8];
    sq[t] = s * s;
    __syncthreads();
    if (t < 8) {
        float n2 = 0.0f;
#pragma unroll
        for (int d = 0; d < 16; ++d) n2 += sq[t * 16 + d];
        fo[t] = sqrtf(n2) / (1.0f + n2);   // ||s|| / (1 + ||s||^2)
    }
    __syncthreads();

    const float v = fo[t >> 4] * s;

    if (PASS == 0)      vsum[(size_t)b * kSeg + od] = v;
    else if (PASS == 1) vsum[(size_t)b * kSeg + od] += v;
    else                out[(size_t)b * kSeg + od] = v;
}

// ---------------------------------------------------------------------------
extern "C" void kernel_launch(void* const* d_in, const int* in_sizes, int n_in,
                              void* d_out, int out_size, void* d_ws, size_t ws_size,
                              hipStream_t stream)
{
    const float* x = (const float*)d_in[0];   // (64, 2048, 8)
    const float* W = (const float*)d_in[1];   // (2048, 32, 16, 8)
    float* out = (float*)d_out;               // (64, 32, 16)

    // ws: bf16 partial [64][256][512] = 16.78 MB, then f32 vsum [64][512]
    __hip_bfloat16* partial = (__hip_bfloat16*)d_ws;
    float* vsum = (float*)((char*)d_ws
                  + (size_t)kB * kNBlocks * kSeg * sizeof(__hip_bfloat16));

    const dim3 gp(kNBlocks), bp(kThreads);
    const dim3 gf(kB * 4), bf(128);

    caps_pass<0><<<gp, bp, 0, stream>>>(x, W, vsum, partial);
    caps_finish<0><<<gf, bf, 0, stream>>>(partial, vsum, out);
    caps_pass<1><<<gp, bp, 0, stream>>>(x, W, vsum, partial);
    caps_finish<1><<<gf, bf, 0, stream>>>(partial, vsum, out);
    caps_pass<2><<<gp, bp, 0, stream>>>(x, W, vsum, partial);
    caps_finish<2><<<gf, bf, 0, stream>>>(partial, vsum, out);
}